// Round 1
// 57.166 us; speedup vs baseline: 1.0322x; 1.0322x over previous
//
#include <hip/hip_runtime.h>
#include <hip/hip_bf16.h>
#include <math.h>

#define HDIM 150

typedef __bf16 bf16x8 __attribute__((ext_vector_type(8)));
typedef __bf16 bf16x4 __attribute__((ext_vector_type(4)));
typedef float  f32x4  __attribute__((ext_vector_type(4)));

__device__ __forceinline__ void async_copy16(const void* g, void* l) {
    __builtin_amdgcn_global_load_lds(
        (const __attribute__((address_space(1))) void*)g,
        (__attribute__((address_space(3))) void*)l, 16, 0, 0);
}

// ---------------------------------------------------------------------------
// k_pack: one block precomputes the per-lane MFMA fragment blob shared by
// every fused-kernel wave. Weights staged into LDS coalesced first; per-lane
// fragment math reads LDS.
// Blob layout (uint4 view): tile i of lane L at blob4[i*64 + L].
// Per lane: dwords 0..39 = fA1[10] (bf16x8), 40..59 = fA2[5], 60..63 = breg.
// ---------------------------------------------------------------------------
__global__ void k_pack(const float* __restrict__ W1, const float* __restrict__ b1,
                       const float* __restrict__ W2, const float* __restrict__ b2,
                       unsigned int* __restrict__ blob)
{
    __shared__ float sW[4050];   // W1 [18][150] | b1 @2700 | W2 [150][8] @2850

    const int t    = threadIdx.x;
    const int lane = t & 63;
    const int c    = t >> 6;        // dword chunk 0..3
    const int m    = lane & 15;
    const int q    = lane >> 4;

    for (int e = t; e < 2700; e += 256) sW[e] = W1[e];
    for (int e = t; e < 150;  e += 256) sW[2700 + e] = b1[e];
    for (int e = t; e < 1200; e += 256) sW[2850 + e] = W2[e];
    __syncthreads();

    for (int d = c * 16; d < c * 16 + 16; ++d) {
        unsigned int word;
        if (d >= 60) {
            word = __float_as_uint(b2[(q & 1) * 4 + (d - 60)]);
        } else {
            float v0 = 0.f, v1 = 0.f;
            if (d < 40) {
                int n = d >> 2, j0 = (d & 3) * 2;
                // permuted hidden rows for the register relay:
                //   tile 2kt   row(4q+r) = hidden 32kt+8q+r
                //   tile 2kt+1 row(4q+r) = hidden 32kt+8q+4+r
                int hid = 32 * (n >> 1) + 8 * (m >> 2) + 4 * (n & 1) + (m & 3);
                if (hid < HDIM) {
                    int k0 = q * 8 + j0, k1 = k0 + 1;
                    v0 = (k0 < 18) ? sW[k0 * HDIM + hid] : (k0 == 18 ? sW[2700 + hid] : 0.f);
                    v1 = (k1 < 18) ? sW[k1 * HDIM + hid] : (k1 == 18 ? sW[2700 + hid] : 0.f);
                }
            } else {
                int kt = (d - 40) >> 2, j0 = ((d - 40) & 3) * 2;
                int k0 = kt * 32 + q * 8 + j0, k1 = k0 + 1;
                if (m < 8) {
                    v0 = (k0 < HDIM) ? sW[2850 + k0 * 8 + m] : 0.f;
                    v1 = (k1 < HDIM) ? sW[2850 + k1 * 8 + m] : 0.f;
                }
            }
            __bf16 h0 = (__bf16)v0, h1 = (__bf16)v1;
            unsigned short u0, u1;
            __builtin_memcpy(&u0, &h0, 2);
            __builtin_memcpy(&u1, &h1, 2);
            word = (unsigned int)u0 | ((unsigned int)u1 << 16);
        }
        blob[(d >> 2) * 256 + lane * 4 + (d & 3)] = word;
    }
}

// ---------------------------------------------------------------------------
// fully unrolled Batcher odd-even mergesort, n = 32
// ---------------------------------------------------------------------------
__device__ __forceinline__ void cswap(float& a, float& b) {
    float lo = fminf(a, b);
    float hi = fmaxf(a, b);
    a = lo; b = hi;
}

__device__ __forceinline__ void sort32(float v[32]) {
#pragma unroll
    for (int pp = 1; pp < 32; pp <<= 1) {
#pragma unroll
        for (int k = pp; k >= 1; k >>= 1) {
#pragma unroll
            for (int j = k & (pp - 1); j + k < 32; j += 2 * k) {
#pragma unroll
                for (int i = 0; i < k; ++i) {
                    if ((i + j) / (2 * pp) == (i + j + k) / (2 * pp))
                        cswap(v[i + j], v[i + j + k]);
                }
            }
        }
    }
}

// ---------------------------------------------------------------------------
// k_fused: per-read MLP (bf16 MFMA register relay) + per-site aggregation +
// head MLP in ONE kernel. Block = 256 threads = 32 sites = 1024 reads.
// h never touches HBM: each wave's MFMA output lands directly in the sH LDS
// layout the aggregation phase consumes (-32 MB HBM round-trip, -1 launch).
// x rows are gathered by read-index via global_load_lds (64B granules), with
// a 2-deep 4KB ring per wave and counted vmcnt(4) so the next group's DMAs
// stay in flight under the current group's MFMA chain.
// LDS overlay: [0,32K) = DMA ring during MLP, reused for sW3B/b3/W4/sAgg in
// the head phase; sH at [32K, 48.5K). 48.5 KB -> 3 blocks/CU.
// ---------------------------------------------------------------------------
#define RING_B   8192                    // per wave: 2 buffers x 4 KB
#define A_BYTES  32768                   // region A (ring | head weights)
#define SH_OFF   A_BYTES                 // sH: 32*264 bf16 = 16896 B
#define W3B_OFF  0                       // bf16[150*48]  = 14400 B
#define B3_OFF   14400                   // float[150]    = 600 B
#define W4_OFF   15000                   // float[150]    = 600 B
#define AGG_OFF  15616                   // float[32*44]  = 5632 B (16-aligned)
#define SMEM_TOTAL (A_BYTES + 16896)     // 49664 B

__global__ __launch_bounds__(256, 3) void k_fused(
    const float* __restrict__ x, const int* __restrict__ kmer,
    const int* __restrict__ indices, const float* __restrict__ emb,
    const unsigned int* __restrict__ blob,
    const float* __restrict__ W3, const float* __restrict__ b3,
    const float* __restrict__ W4, const float* __restrict__ b4,
    float* __restrict__ out, int Gtot)
{
    __shared__ __align__(16) char smem[SMEM_TOTAL];

    const int tid  = threadIdx.x;
    const int lane = tid & 63;
    const int wv   = tid >> 6;
    const int m    = lane & 15;
    const int q    = lane >> 4;

    // ---- fragment blob: 16 coalesced dwordx4 loads (L2-hot) ----
    uint4 B16[16];
    const uint4* bl = (const uint4*)blob;
#pragma unroll
    for (int i = 0; i < 16; ++i) B16[i] = bl[i * 64 + lane];
    const bf16x8* fr = (const bf16x8*)B16;       // fr[0..9]=fA1, fr[10..14]=fA2
    const float4 breg = ((const float4*)B16)[15];

    const int gblk  = blockIdx.x * 32;           // first site of this block
    const int rbase = gblk * 32;                 // first flat read-slot

    // ---- per-wave read indices + emb for 4 groups x 64 reads ----
    int    rg[4];
    float2 eg[4];
    {
        const int lim = Gtot * 32 - 1;
#pragma unroll
        for (int g = 0; g < 4; ++g) {
            int fl = rbase + wv * 256 + g * 64 + lane;
            rg[g] = indices[fl > lim ? lim : fl];
        }
        int kk[4];
#pragma unroll
        for (int g = 0; g < 4; ++g) kk[g] = kmer[rg[g]];
        const float2* emb2 = (const float2*)emb;
#pragma unroll
        for (int g = 0; g < 4; ++g) eg[g] = emb2[kk[g]];
    }

    char* xb = smem + wv * RING_B;
    const char* xg = (const char*)x;
    const int gsw = lane ^ ((lane >> 3) & 7);    // swizzled granule for DMA
    const int rsl = gsw >> 2;                    // read slot in tile (0..15)
    const int rch = gsw & 3;                     // 16B chunk in x row

    // ---- issue group 0 (4 tiles = 4 KB) into buffer 0 ----
#pragma unroll
    for (int tg = 0; tg < 4; ++tg) {
        int rr = __shfl(rg[0], (tg << 4) + rsl);
        async_copy16(xg + (size_t)rr * 64 + (size_t)rch * 16, xb + tg * 1024);
    }

    __bf16* sH = (__bf16*)(smem + SH_OFF);
    const f32x4 zero = {0.f, 0.f, 0.f, 0.f};

#pragma unroll
    for (int g = 0; g < 4; ++g) {
        // prefetch next group into the other buffer, then counted wait so
        // those 4 DMAs stay in flight while we compute this group
        if (g < 3) {
            char* dst = xb + (((g + 1) & 1) << 12);
#pragma unroll
            for (int tg = 0; tg < 4; ++tg) {
                int rr = __shfl(rg[g + 1], (tg << 4) + rsl);
                async_copy16(xg + (size_t)rr * 64 + (size_t)rch * 16, dst + tg * 1024);
            }
            asm volatile("s_waitcnt vmcnt(4)" ::: "memory");
        } else {
            asm volatile("s_waitcnt vmcnt(0)" ::: "memory");
        }

        const char* tb0 = xb + ((g & 1) << 12);
#pragma unroll
        for (int tg = 0; tg < 4; ++tg) {
            float ex = __shfl(eg[g].x, (tg << 4) + m);
            float ey = __shfl(eg[g].y, (tg << 4) + m);

            // input B-fragment: B[k = q*8+j][n = read m]
            bf16x8 bin;
            if (q < 2) {
                int g0 = 4 * m + 2 * q;
                int sx = (g0 >> 3) & 7;
                const char* tb = tb0 + tg * 1024;
                f32x4 u0 = *(const f32x4*)(tb + ((g0       ^ sx) << 4));
                f32x4 u1 = *(const f32x4*)(tb + (((g0 + 1) ^ sx) << 4));
                bin[0] = (__bf16)u0[0]; bin[1] = (__bf16)u0[1];
                bin[2] = (__bf16)u0[2]; bin[3] = (__bf16)u0[3];
                bin[4] = (__bf16)u1[0]; bin[5] = (__bf16)u1[1];
                bin[6] = (__bf16)u1[2]; bin[7] = (__bf16)u1[3];
            } else if (q == 2) {
                bin[0] = (__bf16)ex; bin[1] = (__bf16)ey;
                bin[2] = (__bf16)1.0f;   // bias-1 input at k==18
                bin[3] = (__bf16)0.f; bin[4] = (__bf16)0.f;
                bin[5] = (__bf16)0.f; bin[6] = (__bf16)0.f; bin[7] = (__bf16)0.f;
            } else {
#pragma unroll
                for (int j = 0; j < 8; ++j) bin[j] = (__bf16)0.f;
            }

            // layer1 tile-pair -> relu/pack -> layer2, all in registers.
            f32x4 c2a = zero, c2b = zero;
#pragma unroll
            for (int kt = 0; kt < 5; ++kt) {
                f32x4 ca = __builtin_amdgcn_mfma_f32_16x16x32_bf16(fr[2 * kt],     bin, zero, 0, 0, 0);
                f32x4 cb = __builtin_amdgcn_mfma_f32_16x16x32_bf16(fr[2 * kt + 1], bin, zero, 0, 0, 0);
                bf16x8 bh;
                bh[0] = (__bf16)fmaxf(ca[0], 0.f); bh[1] = (__bf16)fmaxf(ca[1], 0.f);
                bh[2] = (__bf16)fmaxf(ca[2], 0.f); bh[3] = (__bf16)fmaxf(ca[3], 0.f);
                bh[4] = (__bf16)fmaxf(cb[0], 0.f); bh[5] = (__bf16)fmaxf(cb[1], 0.f);
                bh[6] = (__bf16)fmaxf(cb[2], 0.f); bh[7] = (__bf16)fmaxf(cb[3], 0.f);
                if (kt & 1) c2b = __builtin_amdgcn_mfma_f32_16x16x32_bf16(fr[10 + kt], bh, c2b, 0, 0, 0);
                else        c2a = __builtin_amdgcn_mfma_f32_16x16x32_bf16(fr[10 + kt], bh, c2a, 0, 0, 0);
            }

            // h -> LDS (never touches HBM)
            if (q < 2) {
                int br   = wv * 256 + (g * 4 + tg) * 16 + m;   // block read idx
                int site = br >> 5, mm = br & 31;
                bf16x4 o;
                o[0] = (__bf16)fmaxf(c2a[0] + c2b[0] + breg.x, 0.f);
                o[1] = (__bf16)fmaxf(c2a[1] + c2b[1] + breg.y, 0.f);
                o[2] = (__bf16)fmaxf(c2a[2] + c2b[2] + breg.z, 0.f);
                o[3] = (__bf16)fmaxf(c2a[3] + c2b[3] + breg.w, 0.f);
                *(bf16x4*)(sH + site * 264 + mm * 8 + q * 4) = o;
            }
        }
    }
    __syncthreads();   // all h in sH; DMA ring dead -> region A reusable

    // ---- stage head weights into region A; aggregate sites ----
    __bf16* sW3B = (__bf16*)(smem + W3B_OFF);
    float*  sB3  = (float*) (smem + B3_OFF);
    float*  sW4  = (float*) (smem + W4_OFF);
    float*  sAgg = (float*) (smem + AGG_OFF);

    for (int e = tid; e < 40 * HDIM; e += 256) {
        int c = e / HDIM, j = e - c * HDIM;     // W3 row-major [40][150]
        sW3B[j * 48 + c] = (__bf16)W3[e];
    }
    for (int e = tid; e < HDIM; e += 256) { sB3[e] = b3[e]; sW4[e] = W4[e]; }

    const int sg = tid >> 3, p = tid & 7;
    {
        float v[32];
#pragma unroll
        for (int mm = 0; mm < 32; ++mm)
            v[mm] = (float)sH[sg * 264 + mm * 8 + p];

        float sum = 0.f, sumsq = 0.f, mn = v[0], mx = v[0];
#pragma unroll
        for (int mm = 0; mm < 32; ++mm) {
            sum += v[mm];
            sumsq = fmaf(v[mm], v[mm], sumsq);
            mn = fminf(mn, v[mm]);
            mx = fmaxf(mx, v[mm]);
        }
        float mean = sum * (1.f / 32.f);
        float var  = fmaxf((sumsq - 32.f * mean * mean) * (1.f / 31.f), 0.f);
        sort32(v);
        sAgg[sg * 44 + 0 * 8 + p] = mean;
        sAgg[sg * 44 + 1 * 8 + p] = var;
        sAgg[sg * 44 + 2 * 8 + p] = mn;
        sAgg[sg * 44 + 3 * 8 + p] = v[15];   // lower median
        sAgg[sg * 44 + 4 * 8 + p] = mx;
    }
    __syncthreads();

    // ---- head MLP ----
    float ag[40];
#pragma unroll
    for (int c4 = 0; c4 < 10; ++c4) {
        float4 tq = *(const float4*)(sAgg + sg * 44 + c4 * 4);
        ag[c4 * 4 + 0] = tq.x; ag[c4 * 4 + 1] = tq.y;
        ag[c4 * 4 + 2] = tq.z; ag[c4 * 4 + 3] = tq.w;
    }

    float acc = 0.f;
    for (int j = p; j < HDIM; j += 8) {
        const __bf16* wr = sW3B + j * 48;
        float z = sB3[j];
#pragma unroll
        for (int c8 = 0; c8 < 5; ++c8) {
            bf16x8 w = *(const bf16x8*)(wr + c8 * 8);
#pragma unroll
            for (int u = 0; u < 8; ++u)
                z = fmaf(ag[c8 * 8 + u], (float)w[u], z);
        }
        z = fmaxf(z, 0.f);
        acc = fmaf(z, sW4[j], acc);
    }
    acc += __shfl_xor(acc, 1);
    acc += __shfl_xor(acc, 2);
    acc += __shfl_xor(acc, 4);

    if (p == 0 && gblk + sg < Gtot) {
        float zf = acc + b4[0];
        out[gblk + sg] = 1.f / (1.f + expf(-zf));
    }
}

// ---------------------------------------------------------------------------
extern "C" void kernel_launch(void* const* d_in, const int* in_sizes, int n_in,
                              void* d_out, int out_size, void* d_ws, size_t ws_size,
                              hipStream_t stream) {
    const float* x       = (const float*)d_in[0];
    const int*   kmer    = (const int*)  d_in[1];
    const int*   indices = (const int*)  d_in[2];
    const float* emb     = (const float*)d_in[3];
    const float* W1      = (const float*)d_in[4];
    const float* b1      = (const float*)d_in[5];
    const float* W2      = (const float*)d_in[6];
    const float* b2      = (const float*)d_in[7];
    const float* W3      = (const float*)d_in[8];
    const float* b3      = (const float*)d_in[9];
    const float* W4      = (const float*)d_in[10];
    const float* b4      = (const float*)d_in[11];

    float* out = (float*)d_out;
    unsigned int* blob = (unsigned int*)d_ws;    // 16 KB fragment blob

    const int G = out_size;

    k_pack<<<1, 256, 0, stream>>>(W1, b1, W2, b2, blob);

    const int grid = (G + 31) / 32;              // 32 sites / block
    k_fused<<<grid, 256, 0, stream>>>(x, kmer, indices, emb, blob,
                                      W3, b3, W4, b4, out, G);
}

// Round 2
// 47.437 us; speedup vs baseline: 1.2440x; 1.2051x over previous
//
#include <hip/hip_runtime.h>
#include <hip/hip_bf16.h>
#include <math.h>

#define HDIM 150

typedef __bf16 bf16x8 __attribute__((ext_vector_type(8)));
typedef __bf16 bf16x4 __attribute__((ext_vector_type(4)));
typedef float  f32x4  __attribute__((ext_vector_type(4)));

__device__ __forceinline__ void async_copy16(const void* g, void* l) {
    __builtin_amdgcn_global_load_lds(
        (const __attribute__((address_space(1))) void*)g,
        (__attribute__((address_space(3))) void*)l, 16, 0, 0);
}

// ---------------------------------------------------------------------------
// k_pack: one block precomputes every per-lane MFMA fragment blob.
// Blob layout (uint4 view): tile i of lane L at blob4[i*64 + L].
//   tiles 0..15 : layer1/layer2 fragments + b2 (as before)
//   tiles 16..35: head A-fragments  tile 16 + jt*2 + kc  =
//                 A[row = jt*16+m][k = kc*32+q*8+j] = W3[k][jt*16+m] (bf16)
// ---------------------------------------------------------------------------
__global__ void k_pack(const float* __restrict__ W1, const float* __restrict__ b1,
                       const float* __restrict__ W2, const float* __restrict__ b2,
                       const float* __restrict__ W3,
                       unsigned int* __restrict__ blob)
{
    __shared__ float sW[6000];   // phase1: W1|b1@2700|W2@2850 ; phase2: W3[40][150]

    const int t    = threadIdx.x;
    const int lane = t & 63;
    const int c    = t >> 6;        // dword chunk 0..3
    const int m    = lane & 15;
    const int q    = lane >> 4;

    for (int e = t; e < 2700; e += 256) sW[e] = W1[e];
    for (int e = t; e < 150;  e += 256) sW[2700 + e] = b1[e];
    for (int e = t; e < 1200; e += 256) sW[2850 + e] = W2[e];
    __syncthreads();

    for (int d = c * 16; d < c * 16 + 16; ++d) {
        unsigned int word;
        if (d >= 60) {
            word = __float_as_uint(b2[(q & 1) * 4 + (d - 60)]);
        } else {
            float v0 = 0.f, v1 = 0.f;
            if (d < 40) {
                int n = d >> 2, j0 = (d & 3) * 2;
                // permuted hidden rows for the register relay:
                //   tile 2kt   row(4q+r) = hidden 32kt+8q+r
                //   tile 2kt+1 row(4q+r) = hidden 32kt+8q+4+r
                int hid = 32 * (n >> 1) + 8 * (m >> 2) + 4 * (n & 1) + (m & 3);
                if (hid < HDIM) {
                    int k0 = q * 8 + j0, k1 = k0 + 1;
                    v0 = (k0 < 18) ? sW[k0 * HDIM + hid] : (k0 == 18 ? sW[2700 + hid] : 0.f);
                    v1 = (k1 < 18) ? sW[k1 * HDIM + hid] : (k1 == 18 ? sW[2700 + hid] : 0.f);
                }
            } else {
                int kt = (d - 40) >> 2, j0 = ((d - 40) & 3) * 2;
                int k0 = kt * 32 + q * 8 + j0, k1 = k0 + 1;
                if (m < 8) {
                    v0 = (k0 < HDIM) ? sW[2850 + k0 * 8 + m] : 0.f;
                    v1 = (k1 < HDIM) ? sW[2850 + k1 * 8 + m] : 0.f;
                }
            }
            __bf16 h0 = (__bf16)v0, h1 = (__bf16)v1;
            unsigned short u0, u1;
            __builtin_memcpy(&u0, &h0, 2);
            __builtin_memcpy(&u1, &h1, 2);
            word = (unsigned int)u0 | ((unsigned int)u1 << 16);
        }
        blob[(d >> 2) * 256 + lane * 4 + (d & 3)] = word;
    }
    __syncthreads();   // phase-1 reads of sW complete

    // ---- head A-fragments from W3 [40][150] row-major ----
    for (int e = t; e < 6000; e += 256) sW[e] = W3[e];
    __syncthreads();

    for (int f = t; f < 20 * 256; f += 256) {
        int tile  = f >> 8, rem = f & 255;
        int lane2 = rem >> 2, dw = rem & 3;
        int m2 = lane2 & 15, q2 = lane2 >> 4;
        int jt = tile >> 1, kc = tile & 1;
        int row = jt * 16 + m2;
        int k0  = kc * 32 + q2 * 8 + dw * 2;
        float v0 = (k0     < 40 && row < HDIM) ? sW[k0 * HDIM + row] : 0.f;
        float v1 = (k0 + 1 < 40 && row < HDIM) ? sW[(k0 + 1) * HDIM + row] : 0.f;
        __bf16 h0 = (__bf16)v0, h1 = (__bf16)v1;
        unsigned short u0, u1;
        __builtin_memcpy(&u0, &h0, 2);
        __builtin_memcpy(&u1, &h1, 2);
        blob[(16 + tile) * 256 + lane2 * 4 + dw] =
            (unsigned int)u0 | ((unsigned int)u1 << 16);
    }
}

// ---------------------------------------------------------------------------
// fully unrolled Batcher odd-even mergesort, n = 32
// ---------------------------------------------------------------------------
__device__ __forceinline__ void cswap(float& a, float& b) {
    float lo = fminf(a, b);
    float hi = fmaxf(a, b);
    a = lo; b = hi;
}

__device__ __forceinline__ void sort32(float v[32]) {
#pragma unroll
    for (int pp = 1; pp < 32; pp <<= 1) {
#pragma unroll
        for (int k = pp; k >= 1; k >>= 1) {
#pragma unroll
            for (int j = k & (pp - 1); j + k < 32; j += 2 * k) {
#pragma unroll
                for (int i = 0; i < k; ++i) {
                    if ((i + j) / (2 * pp) == (i + j + k) / (2 * pp))
                        cswap(v[i + j], v[i + j + k]);
                }
            }
        }
    }
}

// ---------------------------------------------------------------------------
// k_fused: per-read MLP (bf16 MFMA register relay) + per-site aggregation +
// head MLP in ONE kernel. Block = 256 threads = 32 sites = 1024 reads.
// R10 changes vs R9:
//  * head MLP is now MFMA: Z[150x32] = W3^T @ AGG[40x32] per block, 20 MFMAs
//    per wave (A = precomputed W3 frags; B = agg split into bf16 hi+lo so
//    precision matches the old fp32xbf16 scalar path). Replaces ~1600 scalar
//    VALU ops/thread (incl. 760 redundant bf16->f32 cvts) with ~200.
//  * x-ring halved to 2-tile (2KB) double buffers, sW3B staging removed:
//    LDS 49.6KB -> 33.3KB  => 4 blocks/CU (was 3), zero tail at 4 blk/CU grid.
// LDS overlay: [0,16K) = DMA ring during MLP, reused for sB3/sW4/sAgg/sPart
// in the head phase; sH at [16K, 32.5K).
// ---------------------------------------------------------------------------
#define RING_B   4096                    // per wave: 2 buffers x 2 KB
#define A_BYTES  16384                   // region A (ring | head scratch)
#define SH_OFF   A_BYTES                 // sH: 32*264 bf16 = 16896 B
#define B3_OFF   0                       // float[160] (pad zeroed) = 640 B
#define W4_OFF   640                     // float[160]             = 640 B
#define AGG_OFF  1280                    // float[32*44]           = 5632 B
#define PART_OFF 6912                    // float[32]              = 128 B
#define SMEM_TOTAL (A_BYTES + 16896)     // 33280 B -> 4 blocks/CU

__global__ __launch_bounds__(256, 4) void k_fused(
    const float* __restrict__ x, const int* __restrict__ kmer,
    const int* __restrict__ indices, const float* __restrict__ emb,
    const unsigned int* __restrict__ blob,
    const float* __restrict__ b3, const float* __restrict__ W4,
    const float* __restrict__ b4,
    float* __restrict__ out, int Gtot)
{
    __shared__ __align__(16) char smem[SMEM_TOTAL];

    const int tid  = threadIdx.x;
    const int lane = tid & 63;
    const int wv   = tid >> 6;
    const int m    = lane & 15;
    const int q    = lane >> 4;

    // ---- fragment blob: 16 coalesced dwordx4 loads (L2-hot) ----
    uint4 B16[16];
    const uint4* bl = (const uint4*)blob;
#pragma unroll
    for (int i = 0; i < 16; ++i) B16[i] = bl[i * 64 + lane];
    const bf16x8* fr = (const bf16x8*)B16;       // fr[0..9]=fA1, fr[10..14]=fA2
    const float4 breg = ((const float4*)B16)[15];

    const int gblk  = blockIdx.x * 32;           // first site of this block
    const int rbase = gblk * 32;                 // first flat read-slot

    // ---- per-wave read indices + emb for 4 64-read groups ----
    int    rg[4];
    float2 eg[4];
    {
        const int lim = Gtot * 32 - 1;
#pragma unroll
        for (int g = 0; g < 4; ++g) {
            int fl = rbase + wv * 256 + g * 64 + lane;
            rg[g] = indices[fl > lim ? lim : fl];
        }
        int kk[4];
#pragma unroll
        for (int g = 0; g < 4; ++g) kk[g] = kmer[rg[g]];
        const float2* emb2 = (const float2*)emb;
#pragma unroll
        for (int g = 0; g < 4; ++g) eg[g] = emb2[kk[g]];
    }

    char* xb = smem + wv * RING_B;
    const char* xg = (const char*)x;
    const int gsw = lane ^ ((lane >> 3) & 7);    // swizzled granule for DMA
    const int rsl = gsw >> 2;                    // read slot in tile (0..15)
    const int rch = gsw & 3;                     // 16B chunk in x row

    // ---- prologue: issue group 0 (2 tiles = 2 KB) into buffer 0 ----
#pragma unroll
    for (int tl = 0; tl < 2; ++tl) {
        int rr = __shfl(rg[0], (tl << 4) + rsl);
        async_copy16(xg + (size_t)rr * 64 + (size_t)rch * 16, xb + tl * 1024);
    }

    __bf16* sH = (__bf16*)(smem + SH_OFF);
    const f32x4 zero = {0.f, 0.f, 0.f, 0.f};

#pragma unroll
    for (int gg = 0; gg < 8; ++gg) {
        // prefetch next 2-tile group into the other buffer; counted wait so
        // its 2 DMAs stay in flight while we compute this group
        if (gg < 7) {
            char* dst = xb + (((gg + 1) & 1) << 11);
            int pg = (gg + 1) >> 1, ph = (gg + 1) & 1;
#pragma unroll
            for (int tl = 0; tl < 2; ++tl) {
                int rr = __shfl(rg[pg], ((ph * 2 + tl) << 4) + rsl);
                async_copy16(xg + (size_t)rr * 64 + (size_t)rch * 16, dst + tl * 1024);
            }
            asm volatile("s_waitcnt vmcnt(2)" ::: "memory");
        } else {
            asm volatile("s_waitcnt vmcnt(0)" ::: "memory");
        }

        const char* tb0 = xb + ((gg & 1) << 11);
        const int g4 = gg >> 1, hh = gg & 1;
#pragma unroll
        for (int tl = 0; tl < 2; ++tl) {
            const int tg = hh * 2 + tl;          // tile within 64-read group
            float ex = __shfl(eg[g4].x, (tg << 4) + m);
            float ey = __shfl(eg[g4].y, (tg << 4) + m);

            // input B-fragment: B[k = q*8+j][n = read m]
            bf16x8 bin;
            if (q < 2) {
                int g0 = 4 * m + 2 * q;
                int sx = (g0 >> 3) & 7;
                const char* tb = tb0 + tl * 1024;
                f32x4 u0 = *(const f32x4*)(tb + ((g0       ^ sx) << 4));
                f32x4 u1 = *(const f32x4*)(tb + (((g0 + 1) ^ sx) << 4));
                bin[0] = (__bf16)u0[0]; bin[1] = (__bf16)u0[1];
                bin[2] = (__bf16)u0[2]; bin[3] = (__bf16)u0[3];
                bin[4] = (__bf16)u1[0]; bin[5] = (__bf16)u1[1];
                bin[6] = (__bf16)u1[2]; bin[7] = (__bf16)u1[3];
            } else if (q == 2) {
                bin[0] = (__bf16)ex; bin[1] = (__bf16)ey;
                bin[2] = (__bf16)1.0f;   // bias-1 input at k==18
                bin[3] = (__bf16)0.f; bin[4] = (__bf16)0.f;
                bin[5] = (__bf16)0.f; bin[6] = (__bf16)0.f; bin[7] = (__bf16)0.f;
            } else {
#pragma unroll
                for (int j = 0; j < 8; ++j) bin[j] = (__bf16)0.f;
            }

            // layer1 tile-pair -> relu/pack -> layer2, all in registers.
            f32x4 c2a = zero, c2b = zero;
#pragma unroll
            for (int kt = 0; kt < 5; ++kt) {
                f32x4 ca = __builtin_amdgcn_mfma_f32_16x16x32_bf16(fr[2 * kt],     bin, zero, 0, 0, 0);
                f32x4 cb = __builtin_amdgcn_mfma_f32_16x16x32_bf16(fr[2 * kt + 1], bin, zero, 0, 0, 0);
                bf16x8 bh;
                bh[0] = (__bf16)fmaxf(ca[0], 0.f); bh[1] = (__bf16)fmaxf(ca[1], 0.f);
                bh[2] = (__bf16)fmaxf(ca[2], 0.f); bh[3] = (__bf16)fmaxf(ca[3], 0.f);
                bh[4] = (__bf16)fmaxf(cb[0], 0.f); bh[5] = (__bf16)fmaxf(cb[1], 0.f);
                bh[6] = (__bf16)fmaxf(cb[2], 0.f); bh[7] = (__bf16)fmaxf(cb[3], 0.f);
                if (kt & 1) c2b = __builtin_amdgcn_mfma_f32_16x16x32_bf16(fr[10 + kt], bh, c2b, 0, 0, 0);
                else        c2a = __builtin_amdgcn_mfma_f32_16x16x32_bf16(fr[10 + kt], bh, c2a, 0, 0, 0);
            }

            // h -> LDS (never touches HBM)
            if (q < 2) {
                int br   = wv * 256 + gg * 32 + tl * 16 + m;   // block read idx
                int site = br >> 5, mm = br & 31;
                bf16x4 o;
                o[0] = (__bf16)fmaxf(c2a[0] + c2b[0] + breg.x, 0.f);
                o[1] = (__bf16)fmaxf(c2a[1] + c2b[1] + breg.y, 0.f);
                o[2] = (__bf16)fmaxf(c2a[2] + c2b[2] + breg.z, 0.f);
                o[3] = (__bf16)fmaxf(c2a[3] + c2b[3] + breg.w, 0.f);
                *(bf16x4*)(sH + site * 264 + mm * 8 + q * 4) = o;
            }
        }
    }
    __syncthreads();   // all h in sH; DMA ring dead -> region A reusable

    float* sB3  = (float*)(smem + B3_OFF);
    float* sW4  = (float*)(smem + W4_OFF);
    float* sAgg = (float*)(smem + AGG_OFF);
    float* sPart= (float*)(smem + PART_OFF);

    if (tid < 160) {
        sB3[tid] = (tid < HDIM) ? b3[tid] : 0.f;
        sW4[tid] = (tid < HDIM) ? W4[tid] : 0.f;
    }

    // ---- per-(site,p) aggregation: stats + sort for lower median ----
    const int sg = tid >> 3, p = tid & 7;
    {
        float v[32];
#pragma unroll
        for (int mm = 0; mm < 32; ++mm)
            v[mm] = (float)sH[sg * 264 + mm * 8 + p];

        float sum = 0.f, sumsq = 0.f, mn = v[0], mx = v[0];
#pragma unroll
        for (int mm = 0; mm < 32; ++mm) {
            sum += v[mm];
            sumsq = fmaf(v[mm], v[mm], sumsq);
            mn = fminf(mn, v[mm]);
            mx = fmaxf(mx, v[mm]);
        }
        float mean = sum * (1.f / 32.f);
        float var  = fmaxf((sumsq - 32.f * mean * mean) * (1.f / 31.f), 0.f);
        sort32(v);
        sAgg[sg * 44 + 0 * 8 + p] = mean;
        sAgg[sg * 44 + 1 * 8 + p] = var;
        sAgg[sg * 44 + 2 * 8 + p] = mn;
        sAgg[sg * 44 + 3 * 8 + p] = v[15];   // lower median
        sAgg[sg * 44 + 4 * 8 + p] = mx;
    }

    // ---- head A-fragments (loaded late to keep MLP-phase VGPRs low) ----
    const int jthalf = wv >> 1, sh = wv & 1;
    uint4 HF[10];
#pragma unroll
    for (int i = 0; i < 10; ++i) {
        int jt = jthalf * 5 + (i >> 1), kc = i & 1;
        HF[i] = bl[(16 + jt * 2 + kc) * 64 + lane];
    }
    const bf16x8* hf = (const bf16x8*)HF;
    __syncthreads();

    // ---- head MLP via MFMA: Z[j][site] = W3^T @ AGG, wave = (jthalf, sh) ----
    // B-frag: lane(m,q) holds AGG[k = kc*32+q*8+j][site sh*16+m], split hi/lo
    const int site = sh * 16 + m;
    const float* ar = sAgg + site * 44;
    bf16x8 bh0, bl0, bh1, bl1;
    {
        float4 a0 = *(const float4*)(ar + q * 8);
        float4 a1 = *(const float4*)(ar + q * 8 + 4);
        float va[8] = {a0.x, a0.y, a0.z, a0.w, a1.x, a1.y, a1.z, a1.w};
#pragma unroll
        for (int j = 0; j < 8; ++j) {
            __bf16 hi = (__bf16)va[j];
            bh0[j] = hi;
            bl0[j] = (__bf16)(va[j] - (float)hi);
        }
    }
    if (q == 0) {       // kc=1 covers k = 32..39 (stat 4); other q are zero
        float4 a0 = *(const float4*)(ar + 32);
        float4 a1 = *(const float4*)(ar + 36);
        float va[8] = {a0.x, a0.y, a0.z, a0.w, a1.x, a1.y, a1.z, a1.w};
#pragma unroll
        for (int j = 0; j < 8; ++j) {
            __bf16 hi = (__bf16)va[j];
            bh1[j] = hi;
            bl1[j] = (__bf16)(va[j] - (float)hi);
        }
    } else {
#pragma unroll
        for (int j = 0; j < 8; ++j) { bh1[j] = (__bf16)0.f; bl1[j] = (__bf16)0.f; }
    }

    const float4* b3v = (const float4*)sB3;
    const float4* w4v = (const float4*)sW4;
    float sacc = 0.f;
#pragma unroll
    for (int jj = 0; jj < 5; ++jj) {
        int jt = jthalf * 5 + jj;
        float4 bi = b3v[jt * 4 + q];             // rows jt*16+q*4 .. +3
        f32x4 acc = {bi.x, bi.y, bi.z, bi.w};
        acc = __builtin_amdgcn_mfma_f32_16x16x32_bf16(hf[jj * 2 + 0], bh0, acc, 0, 0, 0);
        acc = __builtin_amdgcn_mfma_f32_16x16x32_bf16(hf[jj * 2 + 0], bl0, acc, 0, 0, 0);
        acc = __builtin_amdgcn_mfma_f32_16x16x32_bf16(hf[jj * 2 + 1], bh1, acc, 0, 0, 0);
        acc = __builtin_amdgcn_mfma_f32_16x16x32_bf16(hf[jj * 2 + 1], bl1, acc, 0, 0, 0);
        float4 w4q = w4v[jt * 4 + q];
        sacc = fmaf(fmaxf(acc[0], 0.f), w4q.x, sacc);
        sacc = fmaf(fmaxf(acc[1], 0.f), w4q.y, sacc);
        sacc = fmaf(fmaxf(acc[2], 0.f), w4q.z, sacc);
        sacc = fmaf(fmaxf(acc[3], 0.f), w4q.w, sacc);
    }
    // reduce over the 4 q row-groups (j within tile), then across jthalf waves
    sacc += __shfl_xor(sacc, 16);
    sacc += __shfl_xor(sacc, 32);
    if (jthalf == 1 && lane < 16) sPart[sh * 16 + lane] = sacc;
    __syncthreads();
    if (jthalf == 0 && lane < 16) {
        int s2 = sh * 16 + lane;
        float zf = sacc + sPart[s2] + b4[0];
        if (gblk + s2 < Gtot) out[gblk + s2] = 1.f / (1.f + expf(-zf));
    }
}

// ---------------------------------------------------------------------------
extern "C" void kernel_launch(void* const* d_in, const int* in_sizes, int n_in,
                              void* d_out, int out_size, void* d_ws, size_t ws_size,
                              hipStream_t stream) {
    const float* x       = (const float*)d_in[0];
    const int*   kmer    = (const int*)  d_in[1];
    const int*   indices = (const int*)  d_in[2];
    const float* emb     = (const float*)d_in[3];
    const float* W1      = (const float*)d_in[4];
    const float* b1      = (const float*)d_in[5];
    const float* W2      = (const float*)d_in[6];
    const float* b2      = (const float*)d_in[7];
    const float* W3      = (const float*)d_in[8];
    const float* b3      = (const float*)d_in[9];
    const float* W4      = (const float*)d_in[10];
    const float* b4      = (const float*)d_in[11];

    float* out = (float*)d_out;
    unsigned int* blob = (unsigned int*)d_ws;    // 36 KB fragment blob

    const int G = out_size;

    k_pack<<<1, 256, 0, stream>>>(W1, b1, W2, b2, W3, blob);

    const int grid = (G + 31) / 32;              // 32 sites / block
    k_fused<<<grid, 256, 0, stream>>>(x, kmer, indices, emb, blob,
                                      b3, W4, b4, out, G);
}